// Round 1
// 352.069 us; speedup vs baseline: 1.0027x; 1.0027x over previous
//
#include <hip/hip_runtime.h>

// Problem UIGen_63058709840320: I=32000, L=2048, D=256.
// Algebraic collapse: out = (weighted[L-2] + weighted[L-1]) @ D2; only rows
// L-2, L-1 of posEmbed/dense1/attention are ever needed.
//
// v2 structure: 4 dispatches, no memsets, no high-contention atomics.
//   k_rows : x rows @ DE -> per-block partials in ws (plain stores);
//            block 0 zeroes dacc/aacc in-kernel.
//   k_d1   : reduce partials (own j-slice) + dense1 chunk -> dacc (16-deep atomics).
//   k_att  : attention chunk -> aacc (16-deep atomics).
//   k_out  : s[d] = da*ta + db*tb; out = s @ D2, block-owned columns,
//            LDS d-reduction, plain float4 stores (no zeroing of out needed).
namespace {
constexpr int LL = 2048;
constexpr int II = 32000;
constexpr int DD = 256;
constexpr int NB = 250;  // k_rows blocks; partials = NB x 512 floats (512 KB)

// ws layout (floats):
//   [0, NB*512)              partials: [blk][row0 d0..255 | row1 d0..255]
//   [NB*512, NB*512+512)     dacc (dense1 rows L-2, L-1)
//   [NB*512+512, NB*512+1024) aacc (attention rows L-2, L-1)

// ---- Kernel A: partials of x[L-2] @ DE and x[L-1] @ DE ----
// 250 blocks x 256 threads; block covers 128 i's; lane = float4 d-group,
// sub = i interleave. LDS-reduce 4 subs, then PLAIN stores to the block's
// partial slot (no atomics, no pre-zero). Block 0 zeroes dacc/aacc so the
// downstream 16-deep atomics have a clean base (stream order guarantees
// visibility at the next kernel launch).
__global__ __launch_bounds__(256) void k_rows(const float* __restrict__ x,
                                              const float* __restrict__ DE,
                                              float* __restrict__ ws) {
  const int lane = threadIdx.x & 63;   // float4 group within D (64 * 4 = 256)
  const int sub  = threadIdx.x >> 6;   // 0..3, i interleave
  const float4* __restrict__ DE4 = reinterpret_cast<const float4*>(DE);
  const float* __restrict__ x0 = x + (size_t)(LL - 2) * II;
  const float* __restrict__ x1 = x + (size_t)(LL - 1) * II;
  const int i0 = blockIdx.x * 128;
  float4 a0 = {0.f, 0.f, 0.f, 0.f};
  float4 a1 = {0.f, 0.f, 0.f, 0.f};
#pragma unroll 8
  for (int ii = 0; ii < 32; ++ii) {
    const int i = i0 + sub + 4 * ii;
    const float4 de = DE4[(size_t)i * (DD / 4) + lane];
    const float s0 = x0[i];
    const float s1 = x1[i];
    a0.x = fmaf(s0, de.x, a0.x);
    a0.y = fmaf(s0, de.y, a0.y);
    a0.z = fmaf(s0, de.z, a0.z);
    a0.w = fmaf(s0, de.w, a0.w);
    a1.x = fmaf(s1, de.x, a1.x);
    a1.y = fmaf(s1, de.y, a1.y);
    a1.z = fmaf(s1, de.z, a1.z);
    a1.w = fmaf(s1, de.w, a1.w);
  }
  __shared__ float red[8][DD];  // [sub*2 + row][d]
  {
    float* r0 = &red[sub * 2 + 0][lane * 4];
    r0[0] = a0.x; r0[1] = a0.y; r0[2] = a0.z; r0[3] = a0.w;
    float* r1 = &red[sub * 2 + 1][lane * 4];
    r1[0] = a1.x; r1[1] = a1.y; r1[2] = a1.z; r1[3] = a1.w;
  }
  __syncthreads();
  const int d = threadIdx.x;
  float* part = ws + (size_t)blockIdx.x * 512;
  part[d]      = red[0][d] + red[2][d] + red[4][d] + red[6][d];
  part[DD + d] = red[1][d] + red[3][d] + red[5][d] + red[7][d];
  if (blockIdx.x == 0) {
    float* dacc = ws + (size_t)NB * 512;
    dacc[d] = 0.f;
    dacc[DD + d] = 0.f;
    dacc[512 + d] = 0.f;       // aacc row 0
    dacc[512 + DD + d] = 0.f;  // aacc row 1
  }
}

// ---- Kernel B1: dense1 rows L-2 (da) and L-1 (db) into dacc[0..511] ----
// dense1[d] = sum_k concat(posEmbed_row, pool1_row)[k] * D1[k][d].
// pool1 is ELEMENTWISE in d: pool1[L-2] = (a+b)/2047, pool1[L-1] = b/2048.
// Each block reduces the 250 partials for its own 32-wide j-slice (64 KB,
// L2/L3-warm) instead of relying on a pre-reduced, atomically-built acc.
__global__ __launch_bounds__(256) void k_d1(const float* __restrict__ part,
                                            const float* __restrict__ PE,
                                            const float* __restrict__ D1,
                                            float* __restrict__ dacc) {
  constexpr int KC = 32;
  __shared__ float reda[8][KC], redb[8][KC];
  __shared__ float va[KC], vb[KC];
  const int k0 = blockIdx.x * KC;
  const int j0 = (k0 < DD) ? k0 : (k0 - DD);
  const int t = threadIdx.x;
  const int jj = t & 31;   // j within slice
  const int pp = t >> 5;   // 0..7 partial interleave
  float sa = 0.f, sb = 0.f;
  for (int p = pp; p < NB; p += 8) {
    const float* pr = part + (size_t)p * 512 + j0 + jj;
    sa += pr[0];
    sb += pr[DD];
  }
  reda[pp][jj] = sa;
  redb[pp][jj] = sb;
  __syncthreads();
  if (t < KC) {
    float a = PE[(size_t)(LL - 2) * DD + j0 + t];
    float b = PE[(size_t)(LL - 1) * DD + j0 + t];
#pragma unroll
    for (int q = 0; q < 8; ++q) {
      a += reda[q][t];
      b += redb[q][t];
    }
    if (k0 < DD) {
      va[t] = a;
      vb[t] = b;
    } else {
      va[t] = (a + b) * (1.0f / (float)(LL - 1));
      vb[t] = b * (1.0f / (float)LL);
    }
  }
  __syncthreads();
  float ra = 0.f, rb = 0.f;
#pragma unroll 8
  for (int kk = 0; kk < KC; ++kk) {
    const float w = D1[(size_t)(k0 + kk) * DD + t];
    ra = fmaf(va[kk], w, ra);
    rb = fmaf(vb[kk], w, rb);
  }
  atomicAdd(&dacc[t], ra);       // 16-deep chains: negligible
  atomicAdd(&dacc[DD + t], rb);
}

// ---- Kernel B2: attention rows L-2/L-1 into aacc[0..511] (same trick) ----
__global__ __launch_bounds__(256) void k_att(const float* __restrict__ dacc,
                                             const float* __restrict__ Att,
                                             float* __restrict__ aacc) {
  constexpr int KC = 32;
  __shared__ float wa[KC], wb[KC];
  const int k0 = blockIdx.x * KC;
  const int t = threadIdx.x;
  if (t < KC) {
    const int k = k0 + t;
    const int j = (k < DD) ? k : (k - DD);
    const float da = dacc[j];
    const float db = dacc[DD + j];
    if (k < DD) {
      wa[t] = da;
      wb[t] = db;
    } else {
      wa[t] = (da + db) * (1.0f / (float)(LL - 1));
      wb[t] = db * (1.0f / (float)LL);
    }
  }
  __syncthreads();
  float ta = 0.f, tb = 0.f;
#pragma unroll 8
  for (int kk = 0; kk < KC; ++kk) {
    const float w = Att[(size_t)(k0 + kk) * DD + t];
    ta = fmaf(wa[kk], w, ta);
    tb = fmaf(wb[kk], w, tb);
  }
  atomicAdd(&aacc[t], ta);
  atomicAdd(&aacc[DD + t], tb);
}

// ---- Kernel C: out[i] = sum_d s[d] * D2[d][i],
//      s[d] = da[d]*ta[d] + db[d]*tb[d]  (weighted[L-2]+weighted[L-1]) ----
// 125 blocks x 256 threads. Block owns 64 float4 i-columns; sub = d-quarter.
// Full d-reduction in-block via LDS, then plain float4 stores: no split-K
// atomics, no pre-zeroed out.
__global__ __launch_bounds__(256) void k_out(const float* __restrict__ dacc,
                                             const float* __restrict__ aacc,
                                             const float* __restrict__ D2,
                                             float* __restrict__ out) {
  __shared__ float sv[DD];
  const int t = threadIdx.x;
  {
    const float da = dacc[t], db = dacc[DD + t];
    const float ta = aacc[t], tb = aacc[DD + t];
    sv[t] = fmaf(da, ta, db * tb);
  }
  __syncthreads();
  const int lane = t & 63;  // i4 within block's 64-wide column group
  const int sub  = t >> 6;  // d quarter (64 d's each)
  const int i4 = blockIdx.x * 64 + lane;  // 125 * 64 = 8000 = II/4
  const float4* __restrict__ D24 = reinterpret_cast<const float4*>(D2);
  float4 a = {0.f, 0.f, 0.f, 0.f};
#pragma unroll 8
  for (int k = 0; k < 64; ++k) {
    const int d = sub * 64 + k;
    const float4 v = D24[(size_t)d * (II / 4) + i4];
    const float sk = sv[d];
    a.x = fmaf(sk, v.x, a.x);
    a.y = fmaf(sk, v.y, a.y);
    a.z = fmaf(sk, v.z, a.z);
    a.w = fmaf(sk, v.w, a.w);
  }
  __shared__ float4 red[4][64];
  red[sub][lane] = a;
  __syncthreads();
  if (t < 64) {
    const float4 r0 = red[0][t], r1 = red[1][t], r2 = red[2][t], r3 = red[3][t];
    float4 o;
    o.x = r0.x + r1.x + r2.x + r3.x;
    o.y = r0.y + r1.y + r2.y + r3.y;
    o.z = r0.z + r1.z + r2.z + r3.z;
    o.w = r0.w + r1.w + r2.w + r3.w;
    reinterpret_cast<float4*>(out)[(size_t)blockIdx.x * 64 + t] = o;
  }
}

}  // namespace

extern "C" void kernel_launch(void* const* d_in, const int* in_sizes, int n_in,
                              void* d_out, int out_size, void* d_ws, size_t ws_size,
                              hipStream_t stream) {
  (void)in_sizes; (void)n_in; (void)ws_size; (void)out_size;
  const float* x   = (const float*)d_in[0];  // [L, I]
  const float* DE  = (const float*)d_in[1];  // [I, D]
  const float* PE  = (const float*)d_in[2];  // [L, D]
  const float* D1  = (const float*)d_in[3];  // [2D, D]
  const float* D2  = (const float*)d_in[4];  // [D, I]
  const float* Att = (const float*)d_in[5];  // [2D, D]
  float* out = (float*)d_out;                // [1, I] fp32
  float* ws = (float*)d_ws;

  float* part = ws;                          // [NB][512] partials
  float* dacc = ws + (size_t)NB * 512;       // [2*D] dense1 rows
  float* aacc = ws + (size_t)NB * 512 + 512; // [2*D] attention rows

  // No memsets: partials are fully written before read; dacc/aacc are zeroed
  // inside k_rows (block 0); out is fully overwritten by plain stores.
  k_rows<<<NB, 256, 0, stream>>>(x, DE, ws);
  k_d1<<<(2 * DD) / 32, 256, 0, stream>>>(part, PE, D1, dacc);   // 16 blocks
  k_att<<<(2 * DD) / 32, 256, 0, stream>>>(dacc, Att, aacc);     // 16 blocks
  k_out<<<II / 4 / 64, 256, 0, stream>>>(dacc, aacc, D2, out);   // 125 blocks
}